// Round 6
// baseline (528.975 us; speedup 1.0000x reference)
//
#include <hip/hip_runtime.h>
#include <cstdint>
#include <cstddef>

// ---------------------------------------------------------------------------
// GraphAttentionHead: out = elu(softmax(mask(LeakyReLU(mu_i + xi_j))) @ h)
// Round 6: two-pass attention.
//   k_wmat: stream adj -> W bf16 [8192x8192] + row-sums Z (exp-free weights
//           via max(Emu*Exi, Fmu*Fxi); pure streaming, max occupancy)
//   k_gatt: plain m97-style GEMM  num = W @ ht^T  (K-split 8, 40KB LDS,
//           acc=64 VGPR, 3-4 blocks/CU)
//   k_final: sum K-partials, /Z, ELU
// Rationale: fused in-loop W-build plateaued at ~140us across 3 structures
// (2 blocks/CU latency wall). These two patterns have measured ceilings.
// ---------------------------------------------------------------------------

#define LOG2E 1.44269504f

typedef __attribute__((ext_vector_type(8))) short short8;   // 8 bf16 = 4 VGPRs
typedef __attribute__((ext_vector_type(4))) float floatx4;  // MFMA acc

using uint_as1 = __attribute__((address_space(1))) unsigned int;
using uint_as3 = __attribute__((address_space(3))) unsigned int;

__device__ __forceinline__ void gld_lds16(const void* g, void* l) {
  __builtin_amdgcn_global_load_lds((const uint_as1*)g, (uint_as3*)l, 16, 0, 0);
}

__device__ __forceinline__ unsigned short f2b(float f) {  // fp32 -> bf16 RNE (finite)
  unsigned u = __float_as_uint(f);
  u += 0x7fffu + ((u >> 16) & 1u);
  return (unsigned short)(u >> 16);
}
__device__ __forceinline__ float b2f(short s) {
  return __uint_as_float(((unsigned)(unsigned short)s) << 16);
}

// --------------------------- K0a: features -> bf16 -------------------------
__global__ void k_cvt_features(const float* __restrict__ f, unsigned short* __restrict__ fb) {
  int tid = blockIdx.x * 256 + threadIdx.x;
  float4 v = ((const float4*)f)[tid];
  ushort4 o = {f2b(v.x), f2b(v.y), f2b(v.z), f2b(v.w)};
  *(ushort4*)&fb[tid * 4] = o;
}

// ------------------- K0b: W_phi [512][256] -> Wt bf16 [256][512] ------------
__global__ void k_prep_wt(const float* __restrict__ w, unsigned short* __restrict__ wt) {
  int tid = blockIdx.x * 256 + threadIdx.x;
  int n = tid >> 9, k = tid & 511;
  wt[n * 512 + k] = f2b(w[k * 256 + n]);
}

// ----------------- K0c: p_mu = W_phi @ w_mu, p_xi = W_phi @ w_xi ------------
__global__ void k_prep_p(const float* __restrict__ w, const float* __restrict__ wmu,
                         const float* __restrict__ wxi, float* __restrict__ pmu,
                         float* __restrict__ pxi) {
  int tid = blockIdx.x * 256 + threadIdx.x;
  int k = tid >> 2, seg = tid & 3;
  float sm = 0.f, sx = 0.f;
  int base = k * 256 + seg * 64;
#pragma unroll
  for (int c = 0; c < 64; c += 4) {
    float4 wv = *(const float4*)&w[base + c];
    float4 mv = *(const float4*)&wmu[seg * 64 + c];
    float4 xv = *(const float4*)&wxi[seg * 64 + c];
    sm += wv.x * mv.x + wv.y * mv.y + wv.z * mv.z + wv.w * mv.w;
    sx += wv.x * xv.x + wv.y * xv.y + wv.z * xv.z + wv.w * xv.w;
  }
  sm += __shfl_xor(sm, 1); sm += __shfl_xor(sm, 2);
  sx += __shfl_xor(sx, 1); sx += __shfl_xor(sx, 2);
  if (seg == 0) { pmu[k] = sm; pxi[k] = sx; }
}

// --- K2: mu/xi matvec, then store Emu=e^mu, Fmu=e^0.2mu, Exi, Fxi -----------
__global__ void k_mu_xi(const unsigned short* __restrict__ fb, const float* __restrict__ pmu,
                        const float* __restrict__ pxi, float* __restrict__ Emu,
                        float* __restrict__ Fmu, float* __restrict__ Exi,
                        float* __restrict__ Fxi) {
  int w = threadIdx.x >> 6, l = threadIdx.x & 63;
  int i = blockIdx.x * 4 + w;
  short8 fv = *(const short8*)&fb[i * 512 + l * 8];
  float m = 0.f, x = 0.f;
#pragma unroll
  for (int c = 0; c < 8; ++c) {
    float fvf = b2f(fv[c]);
    m = fmaf(fvf, pmu[l * 8 + c], m);
    x = fmaf(fvf, pxi[l * 8 + c], x);
  }
#pragma unroll
  for (int off = 32; off > 0; off >>= 1) {
    m += __shfl_xor(m, off);
    x += __shfl_xor(x, off);
  }
  if (l == 0) {
    float ms = m * LOG2E, xs = x * LOG2E;
    Emu[i] = __builtin_amdgcn_exp2f(ms);
    Fmu[i] = __builtin_amdgcn_exp2f(0.2f * ms);
    Exi[i] = __builtin_amdgcn_exp2f(xs);
    Fxi[i] = __builtin_amdgcn_exp2f(0.2f * xs);
  }
}

// ------------- K1: h_t[n][m] = (features @ W_phi)^T, bf16 MFMA --------------
__global__ __launch_bounds__(256, 2) void k_gemm1(const unsigned short* __restrict__ fb,
                                                  const unsigned short* __restrict__ wt,
                                                  unsigned short* __restrict__ ht) {
  __shared__ __align__(16) unsigned short As[64 * 64];
  __shared__ __align__(16) unsigned short Bs[128 * 64];
  int t = threadIdx.x, w = t >> 6, l = t & 63;
  int bm_ = blockIdx.x >> 1, bn = blockIdx.x & 1;
  int m0 = bm_ * 64, n0 = bn * 128;
  int lr = l >> 3, lg = l & 7, g = lg ^ lr;
  int kg = l >> 4, ln = l & 15;
  floatx4 zero = {0.f, 0.f, 0.f, 0.f};
  floatx4 acc[4][2];
#pragma unroll
  for (int mf = 0; mf < 4; ++mf)
#pragma unroll
    for (int nf = 0; nf < 2; ++nf) acc[mf][nf] = zero;

  for (int it = 0; it < 8; ++it) {
    int k0 = it * 64;
#pragma unroll
    for (int q = 0; q < 2; ++q) {
      int row = w * 16 + q * 8 + lr;
      const void* gp = fb + (size_t)(m0 + row) * 512 + k0 + g * 8;
      int lb = __builtin_amdgcn_readfirstlane((w * 16 + q * 8) * 64);
      gld_lds16(gp, &As[lb]);
    }
#pragma unroll
    for (int q = 0; q < 4; ++q) {
      int row = w * 32 + q * 8 + lr;
      const void* gp = wt + (size_t)(n0 + row) * 512 + k0 + g * 8;
      int lb = __builtin_amdgcn_readfirstlane((w * 32 + q * 8) * 64);
      gld_lds16(gp, &Bs[lb]);
    }
    __syncthreads();
#pragma unroll
    for (int ks = 0; ks < 2; ++ks) {
      int gg = ks * 4 + kg;
      int swz = (gg ^ (ln & 7)) * 8;
      short8 bfr[2];
#pragma unroll
      for (int nf = 0; nf < 2; ++nf)
        bfr[nf] = *(const short8*)&Bs[(w * 32 + nf * 16 + ln) * 64 + swz];
#pragma unroll
      for (int mf = 0; mf < 4; ++mf) {
        short8 afr = *(const short8*)&As[(mf * 16 + ln) * 64 + swz];
#pragma unroll
        for (int nf = 0; nf < 2; ++nf)
          acc[mf][nf] = __builtin_amdgcn_mfma_f32_16x16x32_bf16(afr, bfr[nf], acc[mf][nf], 0, 0, 0);
      }
    }
    __syncthreads();
  }
#pragma unroll
  for (int mf = 0; mf < 4; ++mf)
#pragma unroll
    for (int nf = 0; nf < 2; ++nf) {
      int ng = n0 + w * 32 + nf * 16 + ln;
      int mg = m0 + mf * 16 + kg * 4;
      ushort4 o = {f2b(acc[mf][nf][0]), f2b(acc[mf][nf][1]),
                   f2b(acc[mf][nf][2]), f2b(acc[mf][nf][3])};
      *(ushort4*)&ht[(size_t)ng * 8192 + mg] = o;
    }
}

// ------------- K_wmat: adj + E/F -> W bf16 [8192][8192] + Z rowsums ---------
// grid 2048 x 256 thr; wave w -> row i = blk*4 + w; lane l covers 16 j per
// iter, 8 iters. Pure streaming: 268MB read + 134MB write, no barriers.
__global__ __launch_bounds__(256, 4) void k_wmat(const int* __restrict__ adj,
                                                 const float* __restrict__ Emu,
                                                 const float* __restrict__ Fmu,
                                                 const float* __restrict__ Exi,
                                                 const float* __restrict__ Fxi,
                                                 unsigned short* __restrict__ W,
                                                 float* __restrict__ zbuf) {
  int w = threadIdx.x >> 6, l = threadIdx.x & 63;
  int i = blockIdx.x * 4 + w;
  float EM = Emu[i], FM = Fmu[i];
  const int* arow = adj + (size_t)i * 8192;
  unsigned short* wrow = W + (size_t)i * 8192;
  float zacc = 0.f;
#pragma unroll 2
  for (int it = 0; it < 8; ++it) {
    int j = it * 1024 + l * 16;
    const int4* ap = (const int4*)(arow + j);
    int4 a0 = ap[0], a1 = ap[1], a2 = ap[2], a3 = ap[3];
    float4 e0 = *(const float4*)&Exi[j];
    float4 e1 = *(const float4*)&Exi[j + 4];
    float4 e2 = *(const float4*)&Exi[j + 8];
    float4 e3 = *(const float4*)&Exi[j + 12];
    float4 f0 = *(const float4*)&Fxi[j];
    float4 f1 = *(const float4*)&Fxi[j + 4];
    float4 f2 = *(const float4*)&Fxi[j + 8];
    float4 f3 = *(const float4*)&Fxi[j + 12];
    int am[16] = {a0.x, a0.y, a0.z, a0.w, a1.x, a1.y, a1.z, a1.w,
                  a2.x, a2.y, a2.z, a2.w, a3.x, a3.y, a3.z, a3.w};
    float ex[16] = {e0.x, e0.y, e0.z, e0.w, e1.x, e1.y, e1.z, e1.w,
                    e2.x, e2.y, e2.z, e2.w, e3.x, e3.y, e3.z, e3.w};
    float fx[16] = {f0.x, f0.y, f0.z, f0.w, f1.x, f1.y, f1.z, f1.w,
                    f2.x, f2.y, f2.z, f2.w, f3.x, f3.y, f3.z, f3.w};
    short8 p0, p1;
#pragma unroll
    for (int e = 0; e < 16; ++e) {
      float wv = fmaxf(EM * ex[e], FM * fx[e]);
      wv = (am[e] != 0) ? wv : 0.f;
      zacc += wv;
      if (e < 8) p0[e] = (short)f2b(wv); else p1[e - 8] = (short)f2b(wv);
    }
    *(short8*)&wrow[j] = p0;
    *(short8*)&wrow[j + 8] = p1;
  }
#pragma unroll
  for (int off = 32; off > 0; off >>= 1) zacc += __shfl_xor(zacc, off);
  if (l == 0) zbuf[i] = zacc;
}

// ------------- K_gatt: num_partial[jb] = W_tile @ ht^T (m97-style) ----------
// grid 1024 = 128 ibl x 8 ksplit. Block 64i x 256n, K-chunk 1024 (16 iters
// of 64j). LDS 40KB (Ws 8K + Bs 32K) -> 3-4 blocks/CU. acc 4x4 = 64 VGPR.
__global__ __launch_bounds__(256, 3) void k_gatt(const unsigned short* __restrict__ W,
                                                 const unsigned short* __restrict__ ht,
                                                 float* __restrict__ nump) {
  __shared__ __align__(16) unsigned short Ws[64 * 64];    // [i][j'] swizzled, 8 KB
  __shared__ __align__(16) unsigned short Bs[256 * 64];   // [n][j'] swizzled, 32 KB
  int t = threadIdx.x, w = t >> 6, l = t & 63;
  int ln = l & 15, kg = l >> 4;
  int lr = l >> 3, g = (l & 7) ^ lr;            // staging granule swizzle (row = +lr)
  int ib = blockIdx.x & 127, jb = blockIdx.x >> 7;
  int i0 = ib * 64;
  size_t jwin = (size_t)jb * 1024;

  floatx4 zero = {0.f, 0.f, 0.f, 0.f};
  floatx4 acc[4][4];
#pragma unroll
  for (int mf = 0; mf < 4; ++mf)
#pragma unroll
    for (int nf = 0; nf < 4; ++nf) acc[mf][nf] = zero;

  const unsigned short* wbase = W + (size_t)i0 * 8192 + jwin;
  const unsigned short* hbase = ht + jwin;

  for (int c = 0; c < 16; ++c) {
    int jo = c * 64;
    // stage Ws: 64 rows x 128B, 2 gld/wave (HBM stream of W — issue first)
#pragma unroll
    for (int q = 0; q < 2; ++q) {
      int r0 = w * 16 + q * 8;
      const void* gp = wbase + (size_t)(r0 + lr) * 8192 + jo + g * 8;
      int lb = __builtin_amdgcn_readfirstlane(r0 * 64);
      gld_lds16(gp, &Ws[lb]);
    }
    // stage Bs: 256 rows x 128B, 8 gld/wave (L2-resident ht)
#pragma unroll
    for (int q = 0; q < 8; ++q) {
      int r0 = w * 64 + q * 8;
      const void* gp = hbase + (size_t)(r0 + lr) * 8192 + jo + g * 8;
      int lb = __builtin_amdgcn_readfirstlane(r0 * 64);
      gld_lds16(gp, &Bs[lb]);
    }
    __syncthreads();
#pragma unroll
    for (int ks = 0; ks < 2; ++ks) {
      int swz = ((ks * 4 + kg) ^ (ln & 7)) * 8;
      short8 af[4], bf[4];
#pragma unroll
      for (int mf = 0; mf < 4; ++mf)
        af[mf] = *(const short8*)&Ws[(mf * 16 + ln) * 64 + swz];
#pragma unroll
      for (int nf = 0; nf < 4; ++nf)
        bf[nf] = *(const short8*)&Bs[(w * 64 + nf * 16 + ln) * 64 + swz];
#pragma unroll
      for (int mf = 0; mf < 4; ++mf)
#pragma unroll
        for (int nf = 0; nf < 4; ++nf)
          acc[mf][nf] = __builtin_amdgcn_mfma_f32_16x16x32_bf16(af[mf], bf[nf], acc[mf][nf], 0, 0, 0);
    }
    __syncthreads();
  }

  float* np = nump + (size_t)jb * (8192 * 256);
#pragma unroll
  for (int mf = 0; mf < 4; ++mf) {
    int rowb = i0 + mf * 16 + kg * 4;
#pragma unroll
    for (int nf = 0; nf < 4; ++nf) {
      int col = w * 64 + nf * 16 + ln;
#pragma unroll
      for (int r = 0; r < 4; ++r)
        np[(size_t)(rowb + r) * 256 + col] = acc[mf][nf][r];
    }
  }
}

// ---------------- K4: finalize: sum K-partials, /Z, ELU ---------------------
__global__ void k_final(const float* __restrict__ nump, const float* __restrict__ zbuf,
                        float* __restrict__ out) {
  int tid = blockIdx.x * 256 + threadIdx.x;  // x4 floats
  int i = tid >> 6;
  float zi = 1.0f / zbuf[i];
  float4 v = {0.f, 0.f, 0.f, 0.f};
#pragma unroll
  for (int p = 0; p < 8; ++p) {
    float4 s = *(const float4*)&nump[(size_t)p * (8192 * 256) + tid * 4];
    v.x += s.x; v.y += s.y; v.z += s.z; v.w += s.w;
  }
  v.x *= zi; v.y *= zi; v.z *= zi; v.w *= zi;
  v.x = (v.x > 0.f) ? v.x : (__builtin_amdgcn_exp2f(v.x * LOG2E) - 1.f);
  v.y = (v.y > 0.f) ? v.y : (__builtin_amdgcn_exp2f(v.y * LOG2E) - 1.f);
  v.z = (v.z > 0.f) ? v.z : (__builtin_amdgcn_exp2f(v.z * LOG2E) - 1.f);
  v.w = (v.w > 0.f) ? v.w : (__builtin_amdgcn_exp2f(v.w * LOG2E) - 1.f);
  *(float4*)&out[tid * 4] = v;
}

// ---------------------------------------------------------------------------
extern "C" void kernel_launch(void* const* d_in, const int* in_sizes, int n_in,
                              void* d_out, int out_size, void* d_ws, size_t ws_size,
                              hipStream_t stream) {
  const float* features = (const float*)d_in[0];
  const int* adjm = (const int*)d_in[1];
  const float* W_phi = (const float*)d_in[2];
  const float* w_mu = (const float*)d_in[3];
  const float* w_xi = (const float*)d_in[4];
  float* out = (float*)d_out;

  char* ws = (char*)d_ws;
  unsigned short* fb  = (unsigned short*)(ws + 0);         // 8192x512 bf16 = 8 MB
  unsigned short* ht  = (unsigned short*)(ws + 8388608);   // 256x8192 bf16 = 4 MB
  unsigned short* wt  = (unsigned short*)(ws + 12582912);  // 256x512 bf16 = 256 KB
  float* pmu = (float*)(ws + 12845056);                    // 512 f32
  float* pxi = (float*)(ws + 12847104);                    // 512 f32
  float* Emu = (float*)(ws + 12849152);                    // 8192 f32 each
  float* Fmu = (float*)(ws + 12881920);
  float* Exi = (float*)(ws + 12914688);
  float* Fxi = (float*)(ws + 12947456);
  float* zbuf = (float*)(ws + 12980224);                   // 8192 f32
  unsigned short* Wm = (unsigned short*)(ws + 16777216);   // 8192x8192 bf16 = 134 MB
  float* nump = (float*)(ws + 150994944);                  // 8 x 8 MB partials

  k_cvt_features<<<4096, 256, 0, stream>>>(features, fb);
  k_prep_wt<<<512, 256, 0, stream>>>(W_phi, wt);
  k_prep_p<<<8, 256, 0, stream>>>(W_phi, w_mu, w_xi, pmu, pxi);
  k_mu_xi<<<2048, 256, 0, stream>>>(fb, pmu, pxi, Emu, Fmu, Exi, Fxi);
  k_gemm1<<<256, 256, 0, stream>>>(fb, wt, ht);
  k_wmat<<<2048, 256, 0, stream>>>(adjm, Emu, Fmu, Exi, Fxi, Wm, zbuf);
  k_gatt<<<1024, 256, 0, stream>>>(Wm, ht, nump);
  k_final<<<2048, 256, 0, stream>>>(nump, zbuf, out);
}